// Round 6
// baseline (101.734 us; speedup 1.0000x reference)
//
#include <hip/hip_runtime.h>
#include <hip/hip_cooperative_groups.h>
#include <math.h>

namespace cg = cooperative_groups;

#define N 256
#define D 512
#define C 16
#define NBINS 1000
#define MCELL 1000
#define EPSF 1e-9f
// -50/ln(2): exp(-50*q^2) = exp2(KEXP2*q^2)
#define KEXP2 -72.134752f
#define NBLK 128   // 64 blocks per matrix, 4 rows each
#define NTHR 256

__device__ inline float waveReduceSum(float v) {
#pragma unroll
    for (int off = 32; off > 0; off >>= 1) v += __shfl_down(v, off, 64);
    return v;
}
__device__ inline double waveReduceSumD(double v) {
#pragma unroll
    for (int off = 32; off > 0; off >>= 1) v += __shfl_down(v, off, 64);
    return v;
}

// Single cooperative kernel:
//  P1: raw-dot GEMM (4 rows x 256 cols/block) + inv-norm scaling + argmax labels
//      + row E-means + per-cell moment partial (LDS atomics) -> plain-store slice
//  P2: merge 64 slices/mat -> mg
//  P3: Gaussian conv via 2nd-order moment expansion, 16 threads per bin
//  P4: block 0: KLs + order terms
__global__ void __launch_bounds__(NTHR) k_mega(
        const float* __restrict__ T, const float* __restrict__ S,
        const float* __restrict__ labels,
        float* __restrict__ mgp, float* __restrict__ mg,
        float* __restrict__ hp, float* __restrict__ hs,
        float* __restrict__ Earr, float* __restrict__ cpos,
        float* __restrict__ out) {
    cg::grid_group grid = cg::this_grid();
    int b = blockIdx.x;
    int mat = b >> 6;
    int i0 = (b & 63) << 2;
    int j = threadIdx.x;
    int wid = j >> 6, lane = j & 63;

    // sm layout P1: rows[512][4] floats @0 (2048) + mom[6][1024] @2048 (6144)
    //           P3: mg stage (12288)
    __shared__ float sm[12288];
    __shared__ float invs[256];
    __shared__ int labs[256];
    __shared__ float red[4][12];
    __shared__ double dred[4][5];

    const float* X = mat ? S : T;

    // ---- argmax of labels row j (first max, = jnp.argmax) ----
    {
        float best = labels[j * C];
        int bi = 0;
#pragma unroll
        for (int c = 1; c < C; ++c) {
            float v = labels[j * C + c];
            if (v > best) { best = v; bi = c; }
        }
        labs[j] = bi;
    }
    // ---- stage rows[k][r]: thread j holds element j and j+256 of the 4 rows ----
    {
        float4 lo, hi;
        lo.x = X[(i0 + 0) * D + j];
        lo.y = X[(i0 + 1) * D + j];
        lo.z = X[(i0 + 2) * D + j];
        lo.w = X[(i0 + 3) * D + j];
        hi.x = X[(i0 + 0) * D + 256 + j];
        hi.y = X[(i0 + 1) * D + 256 + j];
        hi.z = X[(i0 + 2) * D + 256 + j];
        hi.w = X[(i0 + 3) * D + 256 + j];
        ((float4*)sm)[j] = lo;        // rows[k = j][0..3]
        ((float4*)sm)[j + 256] = hi;  // rows[k = j+256][0..3]
    }
    // zero moment partial
    for (int i = j; i < 6144; i += NTHR) sm[2048 + i] = 0.f;
    __syncthreads();

    // ---- raw dots (4 rows) + own-row sum of squares ----
    float d0 = 0.f, d1 = 0.f, d2 = 0.f, d3 = 0.f, ssq = 0.f;
    {
        const float4* xrow = (const float4*)(X + j * D);
        const float4* rws = (const float4*)sm;
#pragma unroll 8
        for (int k4 = 0; k4 < 128; ++k4) {
            float4 xj = xrow[k4];
            float4 q0 = rws[4 * k4 + 0];
            float4 q1 = rws[4 * k4 + 1];
            float4 q2 = rws[4 * k4 + 2];
            float4 q3 = rws[4 * k4 + 3];
            d0 = fmaf(q0.x, xj.x, fmaf(q1.x, xj.y, fmaf(q2.x, xj.z, fmaf(q3.x, xj.w, d0))));
            d1 = fmaf(q0.y, xj.x, fmaf(q1.y, xj.y, fmaf(q2.y, xj.z, fmaf(q3.y, xj.w, d1))));
            d2 = fmaf(q0.z, xj.x, fmaf(q1.z, xj.y, fmaf(q2.z, xj.z, fmaf(q3.z, xj.w, d2))));
            d3 = fmaf(q0.w, xj.x, fmaf(q1.w, xj.y, fmaf(q2.w, xj.z, fmaf(q3.w, xj.w, d3))));
            ssq = fmaf(xj.x, xj.x, fmaf(xj.y, xj.y, fmaf(xj.z, xj.z, fmaf(xj.w, xj.w, ssq))));
        }
    }
    invs[j] = 1.0f / fmaxf(sqrtf(ssq), 1e-12f);
    __syncthreads();
    float invj = invs[j];
    float av[4];
    av[0] = d0 * invs[i0 + 0] * invj;
    av[1] = d1 * invs[i0 + 1] * invj;
    av[2] = d2 * invs[i0 + 2] * invj;
    av[3] = d3 * invs[i0 + 3] * invj;

    int labj = labs[j];
    float wp[4], vA[4];
#pragma unroll
    for (int r = 0; r < 4; ++r) {
        bool diag = (j == i0 + r);
        wp[r] = (labj == labs[i0 + r] && !diag) ? 1.f : 0.f;
        vA[r] = diag ? 0.f : av[r];
        if (!diag) {  // moment scatter into LDS partial
            float d = av[r];
            int jc = (int)floorf((d + 1.f) * 500.f);
            jc = max(0, min(jc, MCELL - 1));
            float del = d - (-1.f + ((float)jc + 0.5f) * 0.002f);
            float dd = del * del;
            atomicAdd(&sm[2048 + jc], 1.f);
            atomicAdd(&sm[2048 + 1024 + jc], del);
            atomicAdd(&sm[2048 + 2048 + jc], dd);
            if (wp[r] > 0.f) {
                atomicAdd(&sm[2048 + 3072 + jc], 1.f);
                atomicAdd(&sm[2048 + 4096 + jc], del);
                atomicAdd(&sm[2048 + 5120 + jc], dd);
            }
        }
    }

    // ---- row E-sums: 12 independent wave reductions ----
    {
        float r0 = waveReduceSum(vA[0]);
        float r1 = waveReduceSum(av[0] * wp[0]);
        float r2 = waveReduceSum(wp[0]);
        float r3 = waveReduceSum(vA[1]);
        float r4 = waveReduceSum(av[1] * wp[1]);
        float r5 = waveReduceSum(wp[1]);
        float r6 = waveReduceSum(vA[2]);
        float r7 = waveReduceSum(av[2] * wp[2]);
        float r8 = waveReduceSum(wp[2]);
        float r9 = waveReduceSum(vA[3]);
        float r10 = waveReduceSum(av[3] * wp[3]);
        float r11 = waveReduceSum(wp[3]);
        if (lane == 0) {
            red[wid][0] = r0;  red[wid][1] = r1;  red[wid][2] = r2;
            red[wid][3] = r3;  red[wid][4] = r4;  red[wid][5] = r5;
            red[wid][6] = r6;  red[wid][7] = r7;  red[wid][8] = r8;
            red[wid][9] = r9;  red[wid][10] = r10; red[wid][11] = r11;
        }
    }
    __syncthreads();  // mom atomics done + red visible
    if (j < 4) {
        float sA = 0, sP = 0, cP = 0;
        for (int w = 0; w < 4; ++w) {
            sA += red[w][j * 3 + 0];
            sP += red[w][j * 3 + 1];
            cP += red[w][j * 3 + 2];
        }
        int row = i0 + j;
        Earr[(mat * 2 + 0) * N + row] = sP / cP;
        Earr[(mat * 2 + 1) * N + row] = (sA - sP) / (255.f - cP);
        if (mat == 0) cpos[row] = cP;
    }
    // plain-store moment partial slice (deterministic, no init needed)
    {
        float4* dst4 = (float4*)(mgp + (size_t)b * 6144);
        const float4* src4 = (const float4*)(sm + 2048);
        for (int i = j; i < 1536; i += NTHR) dst4[i] = src4[i];
    }

    grid.sync();  // ---- all partials written ----

    // ---- merge 64 slices per mat -> mg (12288 tasks over 32768 threads) ----
    {
        int g = b * NTHR + j;
        if (g < 2 * 6144) {
            int m2 = g >> 13 >= 1 ? 1 : (g >= 6144 ? 1 : 0);  // g/6144
            m2 = g >= 6144 ? 1 : 0;
            int idx = g - m2 * 6144;
            float acc = 0.f;
            const float* src = mgp + (size_t)m2 * 64 * 6144 + idx;
#pragma unroll 8
            for (int s = 0; s < 64; ++s) acc += src[(size_t)s * 6144];
            mg[g] = acc;
        }
    }

    grid.sync();  // ---- mg complete ----

    // ---- conv: stage mg, 16 threads per (mat,bin) ----
    for (int i = j; i < 12288; i += NTHR) sm[i] = mg[i];
    __syncthreads();
    {
        int g = b * NTHR + j;
        int tb = g >> 4;    // 0..2047 (mat*1000+bin tasks, <2000 valid)
        int sub = g & 15;
        if (tb < 2000) {
            int m3 = tb >= 1000 ? 1 : 0;
            int bin = tb - m3 * 1000;
            float t = -1.f + 0.002f * (float)bin;  // bin left edge
            int base = m3 * 6144;
            float pa = 0.f, sa = 0.f;
            for (int c = sub; c < MCELL; c += 16) {
                float m0 = sm[base + c];
                if (m0 == 0.f) continue;
                float cj = -1.f + ((float)c + 0.5f) * 0.002f;
                float q = cj - t;
                float q2 = q * q;
                if (q2 < 0.5f) {  // exp(-50*0.5) ~ 1.4e-11
                    float E = __builtin_amdgcn_exp2f(KEXP2 * q2);
                    float u = 100.f * q;
                    float w2 = fmaf(0.5f * u, u, -50.f);
                    sa = fmaf(E, fmaf(w2, sm[base + 2048 + c],
                                      fmaf(-u, sm[base + 1024 + c], m0)), sa);
                    pa = fmaf(E, fmaf(w2, sm[base + 5120 + c],
                                      fmaf(-u, sm[base + 4096 + c],
                                           sm[base + 3072 + c])), pa);
                }
            }
#pragma unroll
            for (int off = 1; off < 16; off <<= 1) {
                pa += __shfl_xor(pa, off, 16);
                sa += __shfl_xor(sa, off, 16);
            }
            if (sub == 0) {
                hp[tb] = pa;  // [mat*1000 + bin]
                hs[tb] = sa;
            }
        }
    }

    grid.sync();  // ---- histograms complete ----

    if (b != 0) return;

    // ---- final: counts, KLs, order terms (256 threads, double accum) ----
    float cv = cpos[j];
    cv = waveReduceSum(cv);
    if (lane == 0) red[wid][0] = cv;
    __syncthreads();
    float pcnt = red[0][0] + red[1][0] + red[2][0] + red[3][0];
    float ncnt = 65280.f - pcnt;  // N*N - N - pcnt

    double poskl = 0, negkl = 0, o1, o2, o3;
#pragma unroll
    for (int u = 0; u < 4; ++u) {
        int bin = j + u * 256;
        if (bin < NBINS) {
            float hpT = hp[bin], hsT = hs[bin];
            float hpS = hp[1000 + bin], hsS = hs[1000 + bin];
            float pt = hpT / pcnt;
            float nt = (hsT - hpT) / ncnt;
            float ps = hpS / pcnt;
            float ns = (hsS - hpS) / ncnt;
            poskl += (double)((pt + EPSF) * (__logf(pt + EPSF) - __logf(ps + EPSF)));
            negkl += (double)((nt + EPSF) * (__logf(nt + EPSF) - __logf(ns + EPSF)));
        }
    }
    {
        float ept = Earr[0 * N + j];
        float ent = Earr[1 * N + j];
        float eps_ = Earr[2 * N + j];
        float ens = Earr[3 * N + j];
        o1 = fabs((double)ept - (double)eps_);
        o2 = fabs((double)ent - (double)ens);
        o3 = (double)eps_ - (double)ens;
    }
    poskl = waveReduceSumD(poskl);
    negkl = waveReduceSumD(negkl);
    o1 = waveReduceSumD(o1);
    o2 = waveReduceSumD(o2);
    o3 = waveReduceSumD(o3);
    if (lane == 0) {
        dred[wid][0] = poskl; dred[wid][1] = negkl;
        dred[wid][2] = o1; dred[wid][3] = o2; dred[wid][4] = o3;
    }
    __syncthreads();
    if (j == 0) {
        double a = 0, bb = 0, c = 0, d = 0, e = 0;
        for (int w = 0; w < 4; ++w) {
            a += dred[w][0]; bb += dred[w][1];
            c += dred[w][2]; d += dred[w][3]; e += dred[w][4];
        }
        double loss = 0.1 * a + 0.02 * bb + 0.5 * ((c + d + e) / (double)N);
        out[0] = (float)loss;
    }
}

extern "C" void kernel_launch(void* const* d_in, const int* in_sizes, int n_in,
                              void* d_out, int out_size, void* d_ws, size_t ws_size,
                              hipStream_t stream) {
    const float* T = (const float*)d_in[0];
    const float* S = (const float*)d_in[1];
    const float* labels = (const float*)d_in[2];
    float* out = (float*)d_out;

    float* ws = (float*)d_ws;
    float* mgp = ws;                        // NBLK*6144 = 786432
    float* mg = mgp + (size_t)NBLK * 6144;  // 12288
    float* hp = mg + 12288;                 // 2000
    float* hs = hp + 2000;                  // 2000
    float* Earr = hs + 2000;                // 1024
    float* cpos = Earr + 1024;              // 256

    void* args[] = {(void*)&T, (void*)&S, (void*)&labels, (void*)&mgp, (void*)&mg,
                    (void*)&hp, (void*)&hs, (void*)&Earr, (void*)&cpos, (void*)&out};
    hipLaunchCooperativeKernel((const void*)k_mega, dim3(NBLK), dim3(NTHR),
                               args, 0, stream);
}

// Round 7
// 52.556 us; speedup vs baseline: 1.9357x; 1.9357x over previous
//
#include <hip/hip_runtime.h>
#include <math.h>

#define N 256
#define D 512
#define C 16
#define NBINS 1000
#define MCELL 1000
#define MSTRIDE 1024      // per-moment stride inside mg
#define EPSF 1e-9f
// -50/ln(2): exp(-50*q^2) = exp2(KEXP2*q^2)
#define KEXP2 -72.134752f
#define TAILB 64          // tail blocks; 16 bins each, both mats

__device__ inline float waveReduceSum(float v) {
#pragma unroll
    for (int off = 32; off > 0; off >>= 1) v += __shfl_down(v, off, 64);
    return v;
}
__device__ inline double waveReduceSumD(double v) {
#pragma unroll
    for (int off = 32; off > 0; off >>= 1) v += __shfl_down(v, off, 64);
    return v;
}

// L2-normalize rows of T and S -> xn (row major) and xnT (transposed).
// Fused: argmax labels -> lab; first 48 linear blocks zero mg; one thread zeroes cnt.
__global__ void k_prep(const float* __restrict__ T, const float* __restrict__ S,
                       const float* __restrict__ labels,
                       float* __restrict__ xn, float* __restrict__ xnT,
                       int* __restrict__ lab, float* __restrict__ mg,
                       unsigned int* __restrict__ cnt) {
    int i = blockIdx.x;
    int mat = blockIdx.y;
    int tid = threadIdx.x;  // 256
    int bid = mat * 256 + i;
    if (bid < 48) mg[bid * 256 + tid] = 0.f;          // 48*256 = 12288 floats
    if (bid == 48 && tid == 0) cnt[0] = 0u;
    const float* in = mat ? S : T;
    if (mat == 0 && tid == 0) {
        float best = labels[i * C];
        int bi = 0;
#pragma unroll
        for (int c = 1; c < C; ++c) {
            float v = labels[i * C + c];
            if (v > best) { best = v; bi = c; }
        }
        lab[i] = bi;
    }
    float v0 = in[i * D + tid];
    float v1 = in[i * D + 256 + tid];
    float ss = v0 * v0 + v1 * v1;
    ss = waveReduceSum(ss);
    __shared__ float lds[4];
    __shared__ float inv_s;
    int wid = tid >> 6, lane = tid & 63;
    if (lane == 0) lds[wid] = ss;
    __syncthreads();
    if (tid == 0) {
        float tot = lds[0] + lds[1] + lds[2] + lds[3];
        inv_s = 1.0f / fmaxf(sqrtf(tot), 1e-12f);
    }
    __syncthreads();
    float inv = inv_s;
    float* xnm = xn + mat * (N * D);
    float* xnTm = xnT + mat * (N * D);
    float a = v0 * inv, b = v1 * inv;
    xnm[i * D + tid] = a;
    xnm[i * D + 256 + tid] = b;
    xnTm[tid * N + i] = a;
    xnTm[(tid + 256) * N + i] = b;
}

// cos rows + classify + row E-means + moment partial (LDS) + sparse global merge.
// Block = 4 rows x 256 cols. (R5 structure, proven fast.)
__global__ void __launch_bounds__(256) k_main(
        const float* __restrict__ xn, const float* __restrict__ xnT,
        const int* __restrict__ lab, float* __restrict__ mg,
        float* __restrict__ Earr, float* __restrict__ cpos) {
    int mat = blockIdx.y;
    int i0 = blockIdx.x * 4;
    int j = threadIdx.x;  // 256
    const float* xnm = xn + mat * (N * D);
    const float* xc = xnT + mat * (N * D);
    __shared__ float rows[D][4];     // [k][r]: float4 broadcast reads
    __shared__ float mom[6 * 1024];  // m0,m1,m2 (all), m0,m1,m2 (pos)
    for (int i = j; i < 6 * 1024; i += 256) mom[i] = 0.f;
#pragma unroll
    for (int r = 0; r < 4; ++r) {
        rows[j][r] = xnm[(i0 + r) * D + j];
        rows[j + 256][r] = xnm[(i0 + r) * D + 256 + j];
    }
    int labj = lab[j];
    int li0 = lab[i0], li1 = lab[i0 + 1], li2 = lab[i0 + 2], li3 = lab[i0 + 3];
    __syncthreads();

    float a0 = 0.f, a1 = 0.f, a2 = 0.f, a3 = 0.f;
#pragma unroll 8
    for (int k = 0; k < D; ++k) {
        float xb = xc[k * N + j];                 // coalesced
        float4 rr = *(const float4*)&rows[k][0];  // wave-uniform broadcast
        a0 = fmaf(rr.x, xb, a0);
        a1 = fmaf(rr.y, xb, a1);
        a2 = fmaf(rr.z, xb, a2);
        a3 = fmaf(rr.w, xb, a3);
    }
    float av[4] = {a0, a1, a2, a3};
    int liv[4] = {li0, li1, li2, li3};
    float wp[4], vA[4];
#pragma unroll
    for (int r = 0; r < 4; ++r) {
        bool diag = (j == i0 + r);
        wp[r] = (labj == liv[r] && !diag) ? 1.f : 0.f;
        vA[r] = diag ? 0.f : av[r];
        if (!diag) {  // scatter into LDS moment partial
            float d = av[r];
            int jc = (int)floorf((d + 1.f) * 500.f);
            jc = max(0, min(jc, MCELL - 1));
            float del = d - (-1.f + ((float)jc + 0.5f) * 0.002f);
            float dd = del * del;
            atomicAdd(&mom[jc], 1.f);
            atomicAdd(&mom[MSTRIDE + jc], del);
            atomicAdd(&mom[2 * MSTRIDE + jc], dd);
            if (wp[r] > 0.f) {
                atomicAdd(&mom[3 * MSTRIDE + jc], 1.f);
                atomicAdd(&mom[4 * MSTRIDE + jc], del);
                atomicAdd(&mom[5 * MSTRIDE + jc], dd);
            }
        }
    }

    // row E-sums: 12 independent wave reductions
    float r0 = waveReduceSum(vA[0]);
    float r1 = waveReduceSum(av[0] * wp[0]);
    float r2 = waveReduceSum(wp[0]);
    float r3 = waveReduceSum(vA[1]);
    float r4 = waveReduceSum(av[1] * wp[1]);
    float r5 = waveReduceSum(wp[1]);
    float r6 = waveReduceSum(vA[2]);
    float r7 = waveReduceSum(av[2] * wp[2]);
    float r8 = waveReduceSum(wp[2]);
    float r9 = waveReduceSum(vA[3]);
    float r10 = waveReduceSum(av[3] * wp[3]);
    float r11 = waveReduceSum(wp[3]);
    __shared__ float red[4][12];
    int wid = j >> 6, lane = j & 63;
    if (lane == 0) {
        red[wid][0] = r0;  red[wid][1] = r1;  red[wid][2] = r2;
        red[wid][3] = r3;  red[wid][4] = r4;  red[wid][5] = r5;
        red[wid][6] = r6;  red[wid][7] = r7;  red[wid][8] = r8;
        red[wid][9] = r9;  red[wid][10] = r10; red[wid][11] = r11;
    }
    __syncthreads();  // mom atomics done + red visible

    // sparse merge of LDS partial into global mg (~few hundred occupied cells)
    for (int i = j; i < 6 * 1024; i += 256) {
        float v = mom[i];
        if (v != 0.f) atomicAdd(&mg[mat * 6144 + i], v);
    }
    if (j < 4) {
        float sA = 0, sP = 0, cP = 0;
        for (int w = 0; w < 4; ++w) {
            sA += red[w][j * 3 + 0];
            sP += red[w][j * 3 + 1];
            cP += red[w][j * 3 + 2];
        }
        int row = i0 + j;
        Earr[(mat * 2 + 0) * N + row] = sP / cP;
        Earr[(mat * 2 + 1) * N + row] = (sA - sP) / (255.f - cP);
        if (mat == 0) cpos[row] = cP;
    }
}

// Conv (2nd-order moment expansion) for 16 bins x BOTH mats per block,
// per-block KL partials, then last-block ticket computes the final loss.
// e(d,t) ~= E(q) * (m0 - 100q*m1 + (5000q^2-50)*m2), q = cell_center - t
__global__ void __launch_bounds__(256) k_tail(const float* __restrict__ mg,
                                              const float* __restrict__ Earr,
                                              const float* __restrict__ cpos,
                                              float* __restrict__ pkl,
                                              unsigned int* __restrict__ cnt,
                                              float* __restrict__ out) {
    int b = blockIdx.x;
    int tid = threadIdx.x;
    int wid = tid >> 6, lane = tid & 63;
    __shared__ float sm[12288];      // both mats' 6 moments x 1024
    __shared__ float binres[16][4];  // paT, saT, paS, saS
    __shared__ float kterm[16][2];
    __shared__ float credL[4];
    __shared__ unsigned int old_s;
    __shared__ double dred[4][5];

    // stage moments (coalesced float4)
    for (int i = tid; i < 3072; i += 256)
        ((float4*)sm)[i] = ((const float4*)mg)[i];

    // pcnt (redundant per block, deterministic)
    float cv = cpos[tid];
    cv = waveReduceSum(cv);
    if (lane == 0) credL[wid] = cv;
    __syncthreads();
    float pcnt = credL[0] + credL[1] + credL[2] + credL[3];
    float ncnt = 65280.f - pcnt;  // N*N - N - pcnt

    // conv: 16 threads per bin, cells strided by 16; exp shared between mats
    int u = tid >> 4, sub = tid & 15;
    int bin = b * 16 + u;
    float t = -1.f + 0.002f * (float)bin;  // bin left edge
    float paT = 0.f, saT = 0.f, paS = 0.f, saS = 0.f;
    for (int c = sub; c < MCELL; c += 16) {
        float m0T = sm[c], m0S = sm[6144 + c];
        if (m0T == 0.f && m0S == 0.f) continue;
        float cj = -1.f + ((float)c + 0.5f) * 0.002f;
        float q = cj - t;
        float q2 = q * q;
        if (q2 < 0.5f) {  // exp(-50*0.5) ~ 1.4e-11
            float E = __builtin_amdgcn_exp2f(KEXP2 * q2);
            float u1 = 100.f * q;
            float w2 = fmaf(0.5f * u1, u1, -50.f);
            saT = fmaf(E, fmaf(w2, sm[2048 + c], fmaf(-u1, sm[1024 + c], m0T)), saT);
            paT = fmaf(E, fmaf(w2, sm[5120 + c], fmaf(-u1, sm[4096 + c], sm[3072 + c])), paT);
            saS = fmaf(E, fmaf(w2, sm[6144 + 2048 + c], fmaf(-u1, sm[6144 + 1024 + c], m0S)), saS);
            paS = fmaf(E, fmaf(w2, sm[6144 + 5120 + c], fmaf(-u1, sm[6144 + 4096 + c], sm[6144 + 3072 + c])), paS);
        }
    }
#pragma unroll
    for (int off = 1; off < 16; off <<= 1) {
        paT += __shfl_xor(paT, off, 16);
        saT += __shfl_xor(saT, off, 16);
        paS += __shfl_xor(paS, off, 16);
        saS += __shfl_xor(saS, off, 16);
    }
    if (sub == 0) {
        binres[u][0] = paT; binres[u][1] = saT;
        binres[u][2] = paS; binres[u][3] = saS;
    }
    __syncthreads();

    // per-bin KL terms (bin-separable given pcnt/ncnt)
    if (tid < 16) {
        int bn = b * 16 + tid;
        float pk = 0.f, nk = 0.f;
        if (bn < NBINS) {
            float hpT = binres[tid][0], hsT = binres[tid][1];
            float hpS = binres[tid][2], hsS = binres[tid][3];
            float pt = hpT / pcnt;
            float nt = (hsT - hpT) / ncnt;
            float ps = hpS / pcnt;
            float ns = (hsS - hpS) / ncnt;
            pk = (pt + EPSF) * (__logf(pt + EPSF) - __logf(ps + EPSF));
            nk = (nt + EPSF) * (__logf(nt + EPSF) - __logf(ns + EPSF));
        }
        kterm[tid][0] = pk;
        kterm[tid][1] = nk;
    }
    __syncthreads();
    if (tid == 0) {
        float a = 0.f, bb = 0.f;
        for (int q = 0; q < 16; ++q) { a += kterm[q][0]; bb += kterm[q][1]; }
        pkl[b * 2] = a;
        pkl[b * 2 + 1] = bb;
        __threadfence();                     // release: pkl visible device-wide
        old_s = atomicAdd(cnt, 1u);          // ticket
    }
    __syncthreads();
    if (old_s != TAILB - 1) return;

    // ---- last block: final reduction ----
    __threadfence();  // acquire: see all pkl stores
    double a = 0.0, bb = 0.0;
    if (tid < TAILB) {
        volatile const float* vp = pkl;
        a = (double)vp[2 * tid];
        bb = (double)vp[2 * tid + 1];
    }
    a = waveReduceSumD(a);    // wave 0 holds all TAILB entries
    bb = waveReduceSumD(bb);
    double o1, o2, o3;
    {
        float ept = Earr[0 * N + tid];
        float ent = Earr[1 * N + tid];
        float eps_ = Earr[2 * N + tid];
        float ens = Earr[3 * N + tid];
        o1 = fabs((double)ept - (double)eps_);
        o2 = fabs((double)ent - (double)ens);
        o3 = (double)eps_ - (double)ens;
    }
    o1 = waveReduceSumD(o1);
    o2 = waveReduceSumD(o2);
    o3 = waveReduceSumD(o3);
    if (lane == 0) {
        dred[wid][0] = a;  dred[wid][1] = bb;
        dred[wid][2] = o1; dred[wid][3] = o2; dred[wid][4] = o3;
    }
    __syncthreads();
    if (tid == 0) {
        double A = dred[0][0], B = dred[0][1];  // only wave 0 held KL partials
        double Co = 0, Do = 0, Eo = 0;
        for (int w = 0; w < 4; ++w) {
            Co += dred[w][2]; Do += dred[w][3]; Eo += dred[w][4];
        }
        double loss = 0.1 * A + 0.02 * B + 0.5 * ((Co + Do + Eo) / (double)N);
        out[0] = (float)loss;
    }
}

extern "C" void kernel_launch(void* const* d_in, const int* in_sizes, int n_in,
                              void* d_out, int out_size, void* d_ws, size_t ws_size,
                              hipStream_t stream) {
    const float* T = (const float*)d_in[0];
    const float* S = (const float*)d_in[1];
    const float* labels = (const float*)d_in[2];
    float* out = (float*)d_out;

    float* ws = (float*)d_ws;
    float* xn = ws;                      // 2*N*D = 262144
    float* xnT = xn + 2 * N * D;         // 262144
    float* mg = xnT + 2 * N * D;         // 12288
    float* Earr = mg + 12288;            // 1024
    float* cpos = Earr + 1024;           // 256
    float* pkl = cpos + 256;             // 128
    unsigned int* cnt = (unsigned int*)(pkl + 128);  // 1
    int* lab = (int*)(cnt + 1);          // 256 ints

    k_prep<<<dim3(N, 2), 256, 0, stream>>>(T, S, labels, xn, xnT, lab, mg, cnt);
    k_main<<<dim3(N / 4, 2), 256, 0, stream>>>(xn, xnT, lab, mg, Earr, cpos);
    k_tail<<<TAILB, 256, 0, stream>>>(mg, Earr, cpos, pkl, cnt, out);
}

// Round 8
// 48.219 us; speedup vs baseline: 2.1098x; 1.0899x over previous
//
#include <hip/hip_runtime.h>
#include <math.h>

#define N 256
#define D 512
#define C 16
#define NBINS 1000
#define MCELL 1000
#define MSTRIDE 1024      // per-moment stride inside mg
#define EPSF 1e-9f
// -50/ln(2): exp(-50*q^2) = exp2(KEXP2*q^2)
#define KEXP2 -72.134752f
#define TAILB 64          // tail blocks; 16 bins each, both mats

__device__ inline float waveReduceSum(float v) {
#pragma unroll
    for (int off = 32; off > 0; off >>= 1) v += __shfl_down(v, off, 64);
    return v;
}
__device__ inline double waveReduceSumD(double v) {
#pragma unroll
    for (int off = 32; off > 0; off >>= 1) v += __shfl_down(v, off, 64);
    return v;
}

// Tiny prep: blocks 0-11 zero mg (12288 floats), block 12 zeroes ticket + argmax.
__global__ void k_prep(const float* __restrict__ labels, int* __restrict__ lab,
                       float* __restrict__ mg, unsigned int* __restrict__ cnt) {
    int b = blockIdx.x;
    int tid = threadIdx.x;  // 256
    if (b < 12) {
        ((float4*)mg)[b * 256 + tid] = make_float4(0.f, 0.f, 0.f, 0.f);
    } else {
        if (tid == 0) cnt[0] = 0u;
        // lab[i] = argmax_c labels[i,c] (first max, = jnp.argmax)
        float best = labels[tid * C];
        int bi = 0;
#pragma unroll
        for (int c = 1; c < C; ++c) {
            float v = labels[tid * C + c];
            if (v > best) { best = v; bi = c; }
        }
        lab[tid] = bi;
    }
}

// Fused: raw dots vs 2 block rows (direct from T/S) + own-row ssq + inv-norm
// scaling + classification + row E-means + moment scatter + sparse global merge.
// Block = (2 rows, mat); 256 threads = all columns. 256 blocks -> 1/CU.
__global__ void __launch_bounds__(256) k_main(
        const float* __restrict__ T, const float* __restrict__ S,
        const int* __restrict__ lab, float* __restrict__ mg,
        float* __restrict__ Earr, float* __restrict__ cpos) {
    int mat = blockIdx.y;
    int i0 = blockIdx.x * 2;
    int j = threadIdx.x;  // 256
    const float* X = mat ? S : T;
    __shared__ float rowA[D], rowB[D];
    __shared__ float invs[256];
    __shared__ float mom[6 * MSTRIDE];  // m0,m1,m2 (all), m0,m1,m2 (pos)
    __shared__ float red[4][6];
    for (int i = j; i < 6 * MSTRIDE; i += 256) mom[i] = 0.f;
    rowA[j] = X[i0 * D + j];
    rowA[j + 256] = X[i0 * D + 256 + j];
    rowB[j] = X[(i0 + 1) * D + j];
    rowB[j + 256] = X[(i0 + 1) * D + 256 + j];
    __syncthreads();

    // raw dots vs both rows + own-row sum of squares (same fmaf nesting as R6-P1)
    float d0 = 0.f, d1 = 0.f, ssq = 0.f;
    {
        const float4* xrow = (const float4*)(X + (size_t)j * D);
        const float4* rA4 = (const float4*)rowA;
        const float4* rB4 = (const float4*)rowB;
#pragma unroll 16
        for (int k4 = 0; k4 < 128; ++k4) {
            float4 xj = xrow[k4];   // per-thread own row, L1-resident lines
            float4 a4 = rA4[k4];    // wave-uniform LDS broadcast
            float4 b4 = rB4[k4];
            d0 = fmaf(a4.x, xj.x, fmaf(a4.y, xj.y, fmaf(a4.z, xj.z, fmaf(a4.w, xj.w, d0))));
            d1 = fmaf(b4.x, xj.x, fmaf(b4.y, xj.y, fmaf(b4.z, xj.z, fmaf(b4.w, xj.w, d1))));
            ssq = fmaf(xj.x, xj.x, fmaf(xj.y, xj.y, fmaf(xj.z, xj.z, fmaf(xj.w, xj.w, ssq))));
        }
    }
    invs[j] = 1.0f / fmaxf(sqrtf(ssq), 1e-12f);
    __syncthreads();
    float invj = invs[j];
    float av0 = d0 * invs[i0] * invj;
    float av1 = d1 * invs[i0 + 1] * invj;

    int labj = lab[j];
    bool diag0 = (j == i0), diag1 = (j == i0 + 1);
    float wp0 = (labj == lab[i0] && !diag0) ? 1.f : 0.f;
    float wp1 = (labj == lab[i0 + 1] && !diag1) ? 1.f : 0.f;

    // moment scatter into LDS partial (2 dists per thread)
    if (!diag0) {
        int jc = (int)floorf((av0 + 1.f) * 500.f);
        jc = max(0, min(jc, MCELL - 1));
        float del = av0 - (-1.f + ((float)jc + 0.5f) * 0.002f);
        float dd = del * del;
        atomicAdd(&mom[jc], 1.f);
        atomicAdd(&mom[MSTRIDE + jc], del);
        atomicAdd(&mom[2 * MSTRIDE + jc], dd);
        if (wp0 > 0.f) {
            atomicAdd(&mom[3 * MSTRIDE + jc], 1.f);
            atomicAdd(&mom[4 * MSTRIDE + jc], del);
            atomicAdd(&mom[5 * MSTRIDE + jc], dd);
        }
    }
    if (!diag1) {
        int jc = (int)floorf((av1 + 1.f) * 500.f);
        jc = max(0, min(jc, MCELL - 1));
        float del = av1 - (-1.f + ((float)jc + 0.5f) * 0.002f);
        float dd = del * del;
        atomicAdd(&mom[jc], 1.f);
        atomicAdd(&mom[MSTRIDE + jc], del);
        atomicAdd(&mom[2 * MSTRIDE + jc], dd);
        if (wp1 > 0.f) {
            atomicAdd(&mom[3 * MSTRIDE + jc], 1.f);
            atomicAdd(&mom[4 * MSTRIDE + jc], del);
            atomicAdd(&mom[5 * MSTRIDE + jc], dd);
        }
    }

    // row E-sums: 6 independent wave reductions
    float r0 = waveReduceSum(diag0 ? 0.f : av0);
    float r1 = waveReduceSum(av0 * wp0);
    float r2 = waveReduceSum(wp0);
    float r3 = waveReduceSum(diag1 ? 0.f : av1);
    float r4 = waveReduceSum(av1 * wp1);
    float r5 = waveReduceSum(wp1);
    int wid = j >> 6, lane = j & 63;
    if (lane == 0) {
        red[wid][0] = r0; red[wid][1] = r1; red[wid][2] = r2;
        red[wid][3] = r3; red[wid][4] = r4; red[wid][5] = r5;
    }
    __syncthreads();  // mom atomics done + red visible
    if (j < 2) {
        float sA = 0, sP = 0, cP = 0;
        for (int w = 0; w < 4; ++w) {
            sA += red[w][j * 3 + 0];
            sP += red[w][j * 3 + 1];
            cP += red[w][j * 3 + 2];
        }
        int row = i0 + j;
        Earr[(mat * 2 + 0) * N + row] = sP / cP;
        Earr[(mat * 2 + 1) * N + row] = (sA - sP) / (255.f - cP);
        if (mat == 0) cpos[row] = cP;
    }
    // sparse merge of LDS partial into global mg (~couple hundred occupied cells)
    for (int i = j; i < 6 * MSTRIDE; i += 256) {
        float v = mom[i];
        if (v != 0.f) atomicAdd(&mg[mat * 6144 + i], v);
    }
}

// Conv (2nd-order moment expansion) for 16 bins x BOTH mats per block,
// per-block KL partials, then last-block ticket computes the final loss.
// e(d,t) ~= E(q) * (m0 - 100q*m1 + (5000q^2-50)*m2), q = cell_center - t
__global__ void __launch_bounds__(256) k_tail(const float* __restrict__ mg,
                                              const float* __restrict__ Earr,
                                              const float* __restrict__ cpos,
                                              float* __restrict__ pkl,
                                              unsigned int* __restrict__ cnt,
                                              float* __restrict__ out) {
    int b = blockIdx.x;
    int tid = threadIdx.x;
    int wid = tid >> 6, lane = tid & 63;
    __shared__ float sm[12288];      // both mats' 6 moments x 1024
    __shared__ float binres[16][4];  // paT, saT, paS, saS
    __shared__ float kterm[16][2];
    __shared__ float credL[4];
    __shared__ unsigned int old_s;
    __shared__ double dred[4][5];

    // stage moments (coalesced float4)
    for (int i = tid; i < 3072; i += 256)
        ((float4*)sm)[i] = ((const float4*)mg)[i];

    // pcnt (redundant per block, deterministic)
    float cv = cpos[tid];
    cv = waveReduceSum(cv);
    if (lane == 0) credL[wid] = cv;
    __syncthreads();
    float pcnt = credL[0] + credL[1] + credL[2] + credL[3];
    float ncnt = 65280.f - pcnt;  // N*N - N - pcnt

    // conv: 16 threads per bin, cells strided by 16; exp shared between mats
    int u = tid >> 4, sub = tid & 15;
    int bin = b * 16 + u;
    float t = -1.f + 0.002f * (float)bin;  // bin left edge
    float paT = 0.f, saT = 0.f, paS = 0.f, saS = 0.f;
    for (int c = sub; c < MCELL; c += 16) {
        float m0T = sm[c], m0S = sm[6144 + c];
        if (m0T == 0.f && m0S == 0.f) continue;
        float cj = -1.f + ((float)c + 0.5f) * 0.002f;
        float q = cj - t;
        float q2 = q * q;
        if (q2 < 0.5f) {  // exp(-50*0.5) ~ 1.4e-11
            float E = __builtin_amdgcn_exp2f(KEXP2 * q2);
            float u1 = 100.f * q;
            float w2 = fmaf(0.5f * u1, u1, -50.f);
            saT = fmaf(E, fmaf(w2, sm[2048 + c], fmaf(-u1, sm[1024 + c], m0T)), saT);
            paT = fmaf(E, fmaf(w2, sm[5120 + c], fmaf(-u1, sm[4096 + c], sm[3072 + c])), paT);
            saS = fmaf(E, fmaf(w2, sm[6144 + 2048 + c], fmaf(-u1, sm[6144 + 1024 + c], m0S)), saS);
            paS = fmaf(E, fmaf(w2, sm[6144 + 5120 + c], fmaf(-u1, sm[6144 + 4096 + c], sm[6144 + 3072 + c])), paS);
        }
    }
#pragma unroll
    for (int off = 1; off < 16; off <<= 1) {
        paT += __shfl_xor(paT, off, 16);
        saT += __shfl_xor(saT, off, 16);
        paS += __shfl_xor(paS, off, 16);
        saS += __shfl_xor(saS, off, 16);
    }
    if (sub == 0) {
        binres[u][0] = paT; binres[u][1] = saT;
        binres[u][2] = paS; binres[u][3] = saS;
    }
    __syncthreads();

    // per-bin KL terms (bin-separable given pcnt/ncnt)
    if (tid < 16) {
        int bn = b * 16 + tid;
        float pk = 0.f, nk = 0.f;
        if (bn < NBINS) {
            float hpT = binres[tid][0], hsT = binres[tid][1];
            float hpS = binres[tid][2], hsS = binres[tid][3];
            float pt = hpT / pcnt;
            float nt = (hsT - hpT) / ncnt;
            float ps = hpS / pcnt;
            float ns = (hsS - hpS) / ncnt;
            pk = (pt + EPSF) * (__logf(pt + EPSF) - __logf(ps + EPSF));
            nk = (nt + EPSF) * (__logf(nt + EPSF) - __logf(ns + EPSF));
        }
        kterm[tid][0] = pk;
        kterm[tid][1] = nk;
    }
    __syncthreads();
    if (tid == 0) {
        float a = 0.f, bb = 0.f;
        for (int q = 0; q < 16; ++q) { a += kterm[q][0]; bb += kterm[q][1]; }
        pkl[b * 2] = a;
        pkl[b * 2 + 1] = bb;
        __threadfence();                     // release: pkl visible device-wide
        old_s = atomicAdd(cnt, 1u);          // ticket
    }
    __syncthreads();
    if (old_s != TAILB - 1) return;

    // ---- last block: final reduction ----
    __threadfence();  // acquire: see all pkl stores
    double a = 0.0, bb = 0.0;
    if (tid < TAILB) {
        volatile const float* vp = pkl;
        a = (double)vp[2 * tid];
        bb = (double)vp[2 * tid + 1];
    }
    a = waveReduceSumD(a);    // wave 0 holds all TAILB entries
    bb = waveReduceSumD(bb);
    double o1, o2, o3;
    {
        float ept = Earr[0 * N + tid];
        float ent = Earr[1 * N + tid];
        float eps_ = Earr[2 * N + tid];
        float ens = Earr[3 * N + tid];
        o1 = fabs((double)ept - (double)eps_);
        o2 = fabs((double)ent - (double)ens);
        o3 = (double)eps_ - (double)ens;
    }
    o1 = waveReduceSumD(o1);
    o2 = waveReduceSumD(o2);
    o3 = waveReduceSumD(o3);
    if (lane == 0) {
        dred[wid][0] = a;  dred[wid][1] = bb;
        dred[wid][2] = o1; dred[wid][3] = o2; dred[wid][4] = o3;
    }
    __syncthreads();
    if (tid == 0) {
        double A = dred[0][0], B = dred[0][1];  // only wave 0 held KL partials
        double Co = 0, Do = 0, Eo = 0;
        for (int w = 0; w < 4; ++w) {
            Co += dred[w][2]; Do += dred[w][3]; Eo += dred[w][4];
        }
        double loss = 0.1 * A + 0.02 * B + 0.5 * ((Co + Do + Eo) / (double)N);
        out[0] = (float)loss;
    }
}

extern "C" void kernel_launch(void* const* d_in, const int* in_sizes, int n_in,
                              void* d_out, int out_size, void* d_ws, size_t ws_size,
                              hipStream_t stream) {
    const float* T = (const float*)d_in[0];
    const float* S = (const float*)d_in[1];
    const float* labels = (const float*)d_in[2];
    float* out = (float*)d_out;

    float* ws = (float*)d_ws;
    float* mg = ws;                      // 12288
    float* Earr = mg + 12288;            // 1024
    float* cpos = Earr + 1024;           // 256
    float* pkl = cpos + 256;             // 128
    unsigned int* cnt = (unsigned int*)(pkl + 128);  // 1
    int* lab = (int*)(cnt + 1);          // 256 ints

    k_prep<<<13, 256, 0, stream>>>(labels, lab, mg, cnt);
    k_main<<<dim3(N / 2, 2), 256, 0, stream>>>(T, S, lab, mg, Earr, cpos);
    k_tail<<<TAILB, 256, 0, stream>>>(mg, Earr, cpos, pkl, cnt, out);
}

// Round 9
// 48.072 us; speedup vs baseline: 2.1163x; 1.0031x over previous
//
#include <hip/hip_runtime.h>
#include <math.h>

#define N 256
#define D 512
#define C 16
#define NBINS 1000
#define MCELL 1000
#define MSTRIDE 1024      // per-moment stride inside mg
#define EPSF 1e-9f
// -50/ln(2): exp(-50*q^2) = exp2(KEXP2*q^2)
#define KEXP2 -72.134752f
#define TAILB 64          // tail blocks; 16 bins each, both mats

__device__ inline float waveReduceSum(float v) {
#pragma unroll
    for (int off = 32; off > 0; off >>= 1) v += __shfl_down(v, off, 64);
    return v;
}
__device__ inline double waveReduceSumD(double v) {
#pragma unroll
    for (int off = 32; off > 0; off >>= 1) v += __shfl_down(v, off, 64);
    return v;
}

// Tiny prep: blocks 0-11 zero mg (12288 floats), block 12 zeroes ticket + argmax.
__global__ void k_prep(const float* __restrict__ labels, int* __restrict__ lab,
                       float* __restrict__ mg, unsigned int* __restrict__ cnt) {
    int b = blockIdx.x;
    int tid = threadIdx.x;  // 256
    if (b < 12) {
        ((float4*)mg)[b * 256 + tid] = make_float4(0.f, 0.f, 0.f, 0.f);
    } else {
        if (tid == 0) cnt[0] = 0u;
        // lab[i] = argmax_c labels[i,c] (first max, = jnp.argmax)
        float best = labels[tid * C];
        int bi = 0;
#pragma unroll
        for (int c = 1; c < C; ++c) {
            float v = labels[tid * C + c];
            if (v > best) { best = v; bi = c; }
        }
        lab[tid] = bi;
    }
}

// Fused main: 4 rows/block, 512 threads (K split in halves).
// Thread t = (h = t>>8, jj = t&255): partial dots of col jj's K-half vs 4 rows
// + own ssq-half. LDS combine -> full dots + inv norms -> cos. Then classify,
// moment scatter (h=0: rows 0,1; h=1: rows 2,3), row E-means, sparse merge.
__global__ void __launch_bounds__(512) k_main(
        const float* __restrict__ T, const float* __restrict__ S,
        const int* __restrict__ lab, float* __restrict__ mg,
        float* __restrict__ Earr, float* __restrict__ cpos) {
    int mat = blockIdx.y;
    int i0 = blockIdx.x * 4;
    int t = threadIdx.x;           // 512
    int h = t >> 8, jj = t & 255;  // K-half, column
    const float* X = mat ? S : T;

    __shared__ float rows[4 * D];        // 4 staged rows, [r*512+k]
    __shared__ float psum[5][512];       // d0..d3, ssq partials per (jj,h)
    __shared__ float invs[256];
    __shared__ float mom[6 * MSTRIDE];   // m0,m1,m2 (all) + (pos)
    __shared__ float red[8][6];

    for (int i = t; i < 6 * MSTRIDE; i += 512) mom[i] = 0.f;
    // stage 4 rows coalesced: flat f = r*512+k
#pragma unroll
    for (int f = t; f < 4 * D; f += 512) rows[f] = X[i0 * D + f];
    __syncthreads();

    // partial dots over this thread's K-half (256 elems = 64 float4)
    float d0 = 0.f, d1 = 0.f, d2 = 0.f, d3 = 0.f, ssq = 0.f;
    {
        const float4* xrow = (const float4*)(X + (size_t)jj * D + h * 256);
        const float4* r0 = (const float4*)(rows + 0 * D + h * 256);
        const float4* r1 = (const float4*)(rows + 1 * D + h * 256);
        const float4* r2 = (const float4*)(rows + 2 * D + h * 256);
        const float4* r3 = (const float4*)(rows + 3 * D + h * 256);
#pragma unroll 8
        for (int k4 = 0; k4 < 64; ++k4) {
            float4 xj = xrow[k4];   // per-thread own row, L1/L2 lines
            float4 a = r0[k4];      // wave-uniform LDS broadcasts
            float4 b = r1[k4];
            float4 c = r2[k4];
            float4 e = r3[k4];
            d0 = fmaf(a.x, xj.x, fmaf(a.y, xj.y, fmaf(a.z, xj.z, fmaf(a.w, xj.w, d0))));
            d1 = fmaf(b.x, xj.x, fmaf(b.y, xj.y, fmaf(b.z, xj.z, fmaf(b.w, xj.w, d1))));
            d2 = fmaf(c.x, xj.x, fmaf(c.y, xj.y, fmaf(c.z, xj.z, fmaf(c.w, xj.w, d2))));
            d3 = fmaf(e.x, xj.x, fmaf(e.y, xj.y, fmaf(e.z, xj.z, fmaf(e.w, xj.w, d3))));
            ssq = fmaf(xj.x, xj.x, fmaf(xj.y, xj.y, fmaf(xj.z, xj.z, fmaf(xj.w, xj.w, ssq))));
        }
    }
    psum[0][t] = d0; psum[1][t] = d1; psum[2][t] = d2; psum[3][t] = d3;
    psum[4][t] = ssq;
    __syncthreads();
    if (t < 256) {
        float sq = psum[4][t] + psum[4][t + 256];
        invs[t] = 1.0f / fmaxf(sqrtf(sq), 1e-12f);
    }
    __syncthreads();

    float invj = invs[jj];
    float av[4];
#pragma unroll
    for (int r = 0; r < 4; ++r)
        av[r] = (psum[r][jj] + psum[r][jj + 256]) * invs[i0 + r] * invj;

    int labj = lab[jj];
    float wp[4];
#pragma unroll
    for (int r = 0; r < 4; ++r)
        wp[r] = (labj == lab[i0 + r] && jj != i0 + r) ? 1.f : 0.f;

    // moment scatter: h=0 handles rows 0,1; h=1 rows 2,3 (2 dists/thread)
#pragma unroll
    for (int rr = 0; rr < 2; ++rr) {
        int r = h * 2 + rr;
        if (jj != i0 + r) {
            float d = av[r];
            int jc = (int)floorf((d + 1.f) * 500.f);
            jc = max(0, min(jc, MCELL - 1));
            float del = d - (-1.f + ((float)jc + 0.5f) * 0.002f);
            float dd = del * del;
            atomicAdd(&mom[jc], 1.f);
            atomicAdd(&mom[MSTRIDE + jc], del);
            atomicAdd(&mom[2 * MSTRIDE + jc], dd);
            if (wp[r] > 0.f) {
                atomicAdd(&mom[3 * MSTRIDE + jc], 1.f);
                atomicAdd(&mom[4 * MSTRIDE + jc], del);
                atomicAdd(&mom[5 * MSTRIDE + jc], dd);
            }
        }
    }

    // row E-sums: h=0 waves reduce rows 0,1; h=1 waves rows 2,3
    {
        int rA = h * 2, rB = h * 2 + 1;
        float r0v = waveReduceSum((jj != i0 + rA) ? av[rA] : 0.f);
        float r1v = waveReduceSum(av[rA] * wp[rA]);
        float r2v = waveReduceSum(wp[rA]);
        float r3v = waveReduceSum((jj != i0 + rB) ? av[rB] : 0.f);
        float r4v = waveReduceSum(av[rB] * wp[rB]);
        float r5v = waveReduceSum(wp[rB]);
        int wid = t >> 6, lane = t & 63;
        if (lane == 0) {
            red[wid][0] = r0v; red[wid][1] = r1v; red[wid][2] = r2v;
            red[wid][3] = r3v; red[wid][4] = r4v; red[wid][5] = r5v;
        }
    }
    __syncthreads();  // mom atomics done + red visible
    if (t < 4) {
        int wb = (t >> 1) * 4;        // wave bank: rows 0,1 -> waves 0-3; 2,3 -> 4-7
        int sel = (t & 1) * 3;        // 0 or 3 within bank
        float sA = 0, sP = 0, cP = 0;
        for (int w = 0; w < 4; ++w) {
            sA += red[wb + w][sel + 0];
            sP += red[wb + w][sel + 1];
            cP += red[wb + w][sel + 2];
        }
        int row = i0 + t;
        Earr[(mat * 2 + 0) * N + row] = sP / cP;
        Earr[(mat * 2 + 1) * N + row] = (sA - sP) / (255.f - cP);
        if (mat == 0) cpos[row] = cP;
    }
    // sparse merge of LDS partial into global mg
    for (int i = t; i < 6 * MSTRIDE; i += 512) {
        float v = mom[i];
        if (v != 0.f) atomicAdd(&mg[mat * 6144 + i], v);
    }
}

// Conv (2nd-order moment expansion) for 16 bins x BOTH mats per block,
// per-block KL partials, then last-block ticket computes the final loss.
// e(d,t) ~= E(q) * (m0 - 100q*m1 + (5000q^2-50)*m2), q = cell_center - t
__global__ void __launch_bounds__(256) k_tail(const float* __restrict__ mg,
                                              const float* __restrict__ Earr,
                                              const float* __restrict__ cpos,
                                              float* __restrict__ pkl,
                                              unsigned int* __restrict__ cnt,
                                              float* __restrict__ out) {
    int b = blockIdx.x;
    int tid = threadIdx.x;
    int wid = tid >> 6, lane = tid & 63;
    __shared__ float sm[12288];      // both mats' 6 moments x 1024
    __shared__ float binres[16][4];  // paT, saT, paS, saS
    __shared__ float kterm[16][2];
    __shared__ float credL[4];
    __shared__ unsigned int old_s;
    __shared__ double dred[4][5];

    // stage moments (coalesced float4)
    for (int i = tid; i < 3072; i += 256)
        ((float4*)sm)[i] = ((const float4*)mg)[i];

    // pcnt (redundant per block, deterministic)
    float cv = cpos[tid];
    cv = waveReduceSum(cv);
    if (lane == 0) credL[wid] = cv;
    __syncthreads();
    float pcnt = credL[0] + credL[1] + credL[2] + credL[3];
    float ncnt = 65280.f - pcnt;  // N*N - N - pcnt

    // conv: 16 threads per bin, cells strided by 16; exp shared between mats
    int u = tid >> 4, sub = tid & 15;
    int bin = b * 16 + u;
    float t = -1.f + 0.002f * (float)bin;  // bin left edge
    float paT = 0.f, saT = 0.f, paS = 0.f, saS = 0.f;
    for (int c = sub; c < MCELL; c += 16) {
        float m0T = sm[c], m0S = sm[6144 + c];
        if (m0T == 0.f && m0S == 0.f) continue;
        float cj = -1.f + ((float)c + 0.5f) * 0.002f;
        float q = cj - t;
        float q2 = q * q;
        if (q2 < 0.5f) {  // exp(-50*0.5) ~ 1.4e-11
            float E = __builtin_amdgcn_exp2f(KEXP2 * q2);
            float u1 = 100.f * q;
            float w2 = fmaf(0.5f * u1, u1, -50.f);
            saT = fmaf(E, fmaf(w2, sm[2048 + c], fmaf(-u1, sm[1024 + c], m0T)), saT);
            paT = fmaf(E, fmaf(w2, sm[5120 + c], fmaf(-u1, sm[4096 + c], sm[3072 + c])), paT);
            saS = fmaf(E, fmaf(w2, sm[6144 + 2048 + c], fmaf(-u1, sm[6144 + 1024 + c], m0S)), saS);
            paS = fmaf(E, fmaf(w2, sm[6144 + 5120 + c], fmaf(-u1, sm[6144 + 4096 + c], sm[6144 + 3072 + c])), paS);
        }
    }
#pragma unroll
    for (int off = 1; off < 16; off <<= 1) {
        paT += __shfl_xor(paT, off, 16);
        saT += __shfl_xor(saT, off, 16);
        paS += __shfl_xor(paS, off, 16);
        saS += __shfl_xor(saS, off, 16);
    }
    if (sub == 0) {
        binres[u][0] = paT; binres[u][1] = saT;
        binres[u][2] = paS; binres[u][3] = saS;
    }
    __syncthreads();

    // per-bin KL terms (bin-separable given pcnt/ncnt)
    if (tid < 16) {
        int bn = b * 16 + tid;
        float pk = 0.f, nk = 0.f;
        if (bn < NBINS) {
            float hpT = binres[tid][0], hsT = binres[tid][1];
            float hpS = binres[tid][2], hsS = binres[tid][3];
            float pt = hpT / pcnt;
            float nt = (hsT - hpT) / ncnt;
            float ps = hpS / pcnt;
            float ns = (hsS - hpS) / ncnt;
            pk = (pt + EPSF) * (__logf(pt + EPSF) - __logf(ps + EPSF));
            nk = (nt + EPSF) * (__logf(nt + EPSF) - __logf(ns + EPSF));
        }
        kterm[tid][0] = pk;
        kterm[tid][1] = nk;
    }
    __syncthreads();
    if (tid == 0) {
        float a = 0.f, bb = 0.f;
        for (int q = 0; q < 16; ++q) { a += kterm[q][0]; bb += kterm[q][1]; }
        pkl[b * 2] = a;
        pkl[b * 2 + 1] = bb;
        __threadfence();                     // release: pkl visible device-wide
        old_s = atomicAdd(cnt, 1u);          // ticket
    }
    __syncthreads();
    if (old_s != TAILB - 1) return;

    // ---- last block: final reduction ----
    __threadfence();  // acquire: see all pkl stores
    double a = 0.0, bb = 0.0;
    if (tid < TAILB) {
        volatile const float* vp = pkl;
        a = (double)vp[2 * tid];
        bb = (double)vp[2 * tid + 1];
    }
    a = waveReduceSumD(a);    // wave 0 holds all TAILB entries
    bb = waveReduceSumD(bb);
    double o1, o2, o3;
    {
        float ept = Earr[0 * N + tid];
        float ent = Earr[1 * N + tid];
        float eps_ = Earr[2 * N + tid];
        float ens = Earr[3 * N + tid];
        o1 = fabs((double)ept - (double)eps_);
        o2 = fabs((double)ent - (double)ens);
        o3 = (double)eps_ - (double)ens;
    }
    o1 = waveReduceSumD(o1);
    o2 = waveReduceSumD(o2);
    o3 = waveReduceSumD(o3);
    if (lane == 0) {
        dred[wid][0] = a;  dred[wid][1] = bb;
        dred[wid][2] = o1; dred[wid][3] = o2; dred[wid][4] = o3;
    }
    __syncthreads();
    if (tid == 0) {
        double A = dred[0][0], B = dred[0][1];  // only wave 0 held KL partials
        double Co = 0, Do = 0, Eo = 0;
        for (int w = 0; w < 4; ++w) {
            Co += dred[w][2]; Do += dred[w][3]; Eo += dred[w][4];
        }
        double loss = 0.1 * A + 0.02 * B + 0.5 * ((Co + Do + Eo) / (double)N);
        out[0] = (float)loss;
    }
}

extern "C" void kernel_launch(void* const* d_in, const int* in_sizes, int n_in,
                              void* d_out, int out_size, void* d_ws, size_t ws_size,
                              hipStream_t stream) {
    const float* T = (const float*)d_in[0];
    const float* S = (const float*)d_in[1];
    const float* labels = (const float*)d_in[2];
    float* out = (float*)d_out;

    float* ws = (float*)d_ws;
    float* mg = ws;                      // 12288
    float* Earr = mg + 12288;            // 1024
    float* cpos = Earr + 1024;           // 256
    float* pkl = cpos + 256;             // 128
    unsigned int* cnt = (unsigned int*)(pkl + 128);  // 1
    int* lab = (int*)(cnt + 1);          // 256 ints

    k_prep<<<13, 256, 0, stream>>>(labels, lab, mg, cnt);
    k_main<<<dim3(N / 4, 2), 512, 0, stream>>>(T, S, lab, mg, Earr, cpos);
    k_tail<<<TAILB, 256, 0, stream>>>(mg, Earr, cpos, pkl, cnt, out);
}